// Round 5
// baseline (481.303 us; speedup 1.0000x reference)
//
#include <hip/hip_runtime.h>
#include <hip/hip_bf16.h>
#include <math.h>

typedef __attribute__((ext_vector_type(8))) short v8s;   // 8 x bf16 (4 VGPR)
typedef __attribute__((ext_vector_type(4))) short v4sh;  // 4 x bf16
typedef __attribute__((ext_vector_type(4))) float v4f;   // MFMA acc

#define AS1(p) ((const __attribute__((address_space(1))) void*)(p))
#define AS3(p) ((__attribute__((address_space(3))) void*)(p))

__device__ inline unsigned short f2b(float f){
  __hip_bfloat16 h = __float2bfloat16(f);
  return __builtin_bit_cast(unsigned short, h);
}
__device__ inline float b2f(unsigned short u){
  __hip_bfloat16 h = __builtin_bit_cast(__hip_bfloat16, u);
  return __bfloat162float(h);
}

// id(table index i), delta = i - 1023
__device__ inline int bucket_id(int i){
  int r = i - 1023;
  if (r > 511) r = 511; if (r < -511) r = -511;
  float sign = (r > 0) ? 1.f : ((r < 0) ? -1.f : 0.f);
  int ap = r < 0 ? -r : r; if (ap < 1) ap = 1;
  float bucket;
  if (ap < 128) bucket = (float)ap * sign;
  else {
    float lp = ceilf(logf((float)ap / 128.f) / logf(511.f/128.f) * 127.f) + 128.f;
    bucket = lp * sign;
  }
  int idx = (int)bucket + 256;
  if (idx < 0) idx = 0; if (idx > 511) idx = 511;
  return idx;
}

// ------- prep: f32 -> bf16 pack of [hidden ; rel] + idx tables tail --------
__global__ __launch_bounds__(256) void pack_x(const float* __restrict__ hs,
                                              const float* __restrict__ rel,
                                              unsigned short* __restrict__ X,
                                              short* __restrict__ tab,
                                              unsigned long long* __restrict__ tab64){
  int blk = blockIdx.x;
  if (blk >= 2304){
    int i = (blk - 2304)*256 + threadIdx.x;
    if (i < 2047) tab[i] = (short)bucket_id(i);
    if (i < 2056){
      unsigned long long w = 0;
      #pragma unroll
      for (int r = 0; r < 4; r++)
        w |= (unsigned long long)(unsigned short)bucket_id(i + r) << (16*r);
      tab64[i] = w;
    }
    return;
  }
  const int HT8 = 4096*1024/8;
  int i8 = blk*256 + threadIdx.x;
  const float* src = (i8 < HT8) ? (hs + (size_t)i8*8) : (rel + ((size_t)i8 - HT8)*8);
  v8s o;
  #pragma unroll
  for (int j = 0; j < 8; j++) o[j] = (short)f2b(src[j]);
  *(v8s*)&X[(size_t)i8*8] = o;
}

// ---------------- transpose f32 -> bf16, all three weights -----------------
__global__ __launch_bounds__(256) void transp3(const float* __restrict__ Wq,
                                               const float* __restrict__ Wk,
                                               const float* __restrict__ Wv,
                                               unsigned short* __restrict__ out){
  __shared__ unsigned short t[64][65];
  const float* in = (blockIdx.y == 0) ? Wq : ((blockIdx.y == 1) ? Wk : Wv);
  out += (size_t)blockIdx.y << 20;
  int r0 = (blockIdx.x >> 4) << 6, c0 = (blockIdx.x & 15) << 6;
  int tx = threadIdx.x & 63, ty = threadIdx.x >> 6;
  #pragma unroll
  for (int p = 0; p < 16; p++){ int r = (p<<2)+ty; t[tx][r] = f2b(in[(size_t)(r0+r)*1024 + c0+tx]); }
  __syncthreads();
  #pragma unroll
  for (int p = 0; p < 16; p++){ int c = (p<<2)+ty; out[(size_t)(c0+c)*1024 + r0+tx] = t[c][tx]; }
}

// ---------------- transpose bf16 1024x1024 per batch (V -> V^T) ------------
__global__ __launch_bounds__(256) void transp_b(const unsigned short* __restrict__ in,
                                                unsigned short* __restrict__ out){
  __shared__ unsigned short t[64][65];
  size_t base = (size_t)blockIdx.z << 20;
  int r0 = (blockIdx.x >> 4) << 6, c0 = (blockIdx.x & 15) << 6;
  int tx = threadIdx.x & 63, ty = threadIdx.x >> 6;
  #pragma unroll
  for (int p = 0; p < 16; p++){ int r = (p<<2)+ty; t[tx][r] = in[base + (size_t)(r0+r)*1024 + c0+tx]; }
  __syncthreads();
  #pragma unroll
  for (int p = 0; p < 16; p++){ int c = (p<<2)+ty; out[base + (size_t)(c0+c)*1024 + r0+tx] = t[c][tx]; }
}

// ---------------- merged QKV GEMM: [Xb 4608x1024] @ [Wt3 3072x1024]^T ------
__global__ __launch_bounds__(256) void gemm_qkv(
    const unsigned short* __restrict__ A,    // [4608][1024]
    const unsigned short* __restrict__ Bt3,  // [3072][1024] rows = out cols
    unsigned short* __restrict__ Qa, unsigned short* __restrict__ Ka,
    unsigned short* __restrict__ Va,
    const float* __restrict__ bq, const float* __restrict__ bk,
    const float* __restrict__ bv, float alpha_q)
{
  __shared__ unsigned short a_tile[128*64];
  __shared__ unsigned short b_tile[128*64];
  int nb = (blockIdx.x & 7)*108 + (blockIdx.x >> 3);   // XCD swizzle (864 = 8*108)
  int bm = nb / 24, bn = nb % 24;
  int m0 = bm << 7, n0 = bn << 7;
  int tid = threadIdx.x, lane = tid & 63, wave = tid >> 6;
  int l15 = lane & 15, lhi = lane >> 4;
  int rbase = (wave >> 1) << 6, cbase = (wave & 1) << 6;
  int crow[4], csw[4];
  #pragma unroll
  for (int u = 0; u < 4; u++){
    int ch = tid + (u << 8);
    crow[u] = ch >> 3;
    csw[u] = ((ch & 7) ^ (crow[u] & 7)) << 3;
  }
  v4f acc[4][4] = {};
  for (int kt = 0; kt < 1024; kt += 64){
    #pragma unroll
    for (int u = 0; u < 4; u++){
      int ch = tid + (u << 8);
      __builtin_amdgcn_global_load_lds(AS1(A   + (size_t)(m0 + crow[u])*1024 + kt + csw[u]),
                                       AS3(a_tile + (size_t)ch*8), 16, 0, 0);
      __builtin_amdgcn_global_load_lds(AS1(Bt3 + (size_t)(n0 + crow[u])*1024 + kt + csw[u]),
                                       AS3(b_tile + (size_t)ch*8), 16, 0, 0);
    }
    __syncthreads();
    #pragma unroll
    for (int ks = 0; ks < 2; ks++){
      v8s af[4], bfr[4];
      int kb = (ks << 2) + lhi;
      #pragma unroll
      for (int i = 0; i < 4; i++){
        int r = rbase + (i << 4) + l15;
        af[i] = *(const v8s*)&a_tile[r*64 + ((kb ^ (r & 7)) << 3)];
      }
      #pragma unroll
      for (int j = 0; j < 4; j++){
        int r = cbase + (j << 4) + l15;
        bfr[j] = *(const v8s*)&b_tile[r*64 + ((kb ^ (r & 7)) << 3)];
      }
      #pragma unroll
      for (int i = 0; i < 4; i++)
        #pragma unroll
        for (int j = 0; j < 4; j++)
          acc[i][j] = __builtin_amdgcn_mfma_f32_16x16x32_bf16(af[i], bfr[j], acc[i][j], 0, 0, 0);
    }
    __syncthreads();
  }
  int seg = n0 >> 10;
  unsigned short* C = (seg == 0) ? Qa : ((seg == 1) ? Ka : Va);
  const float* bias = (seg == 0) ? bq : ((seg == 1) ? bk : bv);
  float alpha = (seg == 0) ? alpha_q : 1.f;
  int nn0 = n0 & 1023;
  #pragma unroll
  for (int i = 0; i < 4; i++){
    int row = m0 + rbase + (i << 4) + (lhi << 2);
    #pragma unroll
    for (int j = 0; j < 4; j++){
      int col = nn0 + cbase + (j << 4) + l15;
      float bvv = bias[col];
      #pragma unroll
      for (int r = 0; r < 4; r++)
        C[(size_t)(row + r)*1024 + col] = f2b((acc[i][j][r] + bvv) * alpha);
    }
  }
}

// ---------------- merged pos GEMMs: c2p & p2c, K=64, per head --------------
__global__ __launch_bounds__(256) void gemm_pos(
    const unsigned short* __restrict__ Qa,   // [4608][1024] (scaled)
    const unsigned short* __restrict__ Ka,   // [4608][1024]
    unsigned short* __restrict__ C2P,        // [4096][8192]
    unsigned short* __restrict__ P2C)        // [4096][8192]
{
  __shared__ unsigned short a_tile[128*64];
  __shared__ unsigned short b_tile[128*64];
  int tab = blockIdx.y >> 4, h = blockIdx.y & 15;
  int bm = blockIdx.x >> 2, bn = blockIdx.x & 3;
  int m0 = bm << 7, n0 = bn << 7;
  const unsigned short* A  = tab ? Ka : Qa;
  const unsigned short* Bt = tab ? Qa : Ka;
  unsigned short* C = tab ? P2C : C2P;
  int tid = threadIdx.x, lane = tid & 63, wave = tid >> 6;
  int l15 = lane & 15, lhi = lane >> 4;
  int rbase = (wave >> 1) << 6, cbase = (wave & 1) << 6;
  #pragma unroll
  for (int u = 0; u < 4; u++){
    int ch = tid + (u << 8);
    int row = ch >> 3;
    int csw = ((ch & 7) ^ (row & 7)) << 3;
    __builtin_amdgcn_global_load_lds(AS1(A  + (size_t)(m0 + row)*1024 + (h << 6) + csw),
                                     AS3(a_tile + (size_t)ch*8), 16, 0, 0);
    __builtin_amdgcn_global_load_lds(AS1(Bt + (size_t)(4096 + n0 + row)*1024 + (h << 6) + csw),
                                     AS3(b_tile + (size_t)ch*8), 16, 0, 0);
  }
  __syncthreads();
  v4f acc[4][4] = {};
  #pragma unroll
  for (int ks = 0; ks < 2; ks++){
    v8s af[4], bfr[4];
    int kb = (ks << 2) + lhi;
    #pragma unroll
    for (int i = 0; i < 4; i++){
      int r = rbase + (i << 4) + l15;
      af[i] = *(const v8s*)&a_tile[r*64 + ((kb ^ (r & 7)) << 3)];
    }
    #pragma unroll
    for (int j = 0; j < 4; j++){
      int r = cbase + (j << 4) + l15;
      bfr[j] = *(const v8s*)&b_tile[r*64 + ((kb ^ (r & 7)) << 3)];
    }
    #pragma unroll
    for (int i = 0; i < 4; i++)
      #pragma unroll
      for (int j = 0; j < 4; j++)
        acc[i][j] = __builtin_amdgcn_mfma_f32_16x16x32_bf16(af[i], bfr[j], acc[i][j], 0, 0, 0);
  }
  #pragma unroll
  for (int i = 0; i < 4; i++){
    int row = m0 + rbase + (i << 4) + (lhi << 2);
    #pragma unroll
    for (int j = 0; j < 4; j++){
      int col = n0 + cbase + (j << 4) + l15;
      #pragma unroll
      for (int r = 0; r < 4; r++)
        C[(size_t)(row + r)*8192 + (h << 9) + col] = f2b(acc[i][j][r]);
    }
  }
}

// ---------------- fused disentangled flash attention -----------------------
// 1024 blocks (XCD-swizzled), 256 thr = 4 waves, 64 q rows/block.
// LDS 34.3 KB -> 4 blocks/CU (16 waves). P is overlaid into cw's own-wave
// rows (bias-read and P-write/PV-read are same-wave, program-ordered).
__global__ __launch_bounds__(256, 4) void attn(
  const unsigned short* __restrict__ Qall,   // [4608][1024] (scaled by log2e/sqrt(192))
  const unsigned short* __restrict__ Kall,   // [4608][1024]
  const unsigned short* __restrict__ Vt,     // [4096][1024]: row=b*1024+h*64+d, col=s
  const unsigned short* __restrict__ c2p,    // [4096][8192]
  const unsigned short* __restrict__ p2c,    // [4096][8192]
  const short* __restrict__ idxt,            // [2047]
  const unsigned long long* __restrict__ t64g, // [2056] packed ids i..i+3
  float* __restrict__ out)                   // [4][1024][1024] f32
{
  __shared__ unsigned short k_lds[64*64];    // 8 KB
  __shared__ unsigned short v_lds[64*64];    // 8 KB
  __shared__ unsigned short cw[64*72];       // 9 KB   c2p windows; P overlaid per-wave
  __shared__ unsigned short pw[64*72];       // 9 KB   p2c windows
  __shared__ unsigned short ws8c[64];        // per-row window bases (q rows)
  __shared__ unsigned short ws8p[64];        // per-row window bases (k rows)

  // XCD-aware swizzle: all 16 q-blocks of one (b,h) on one XCD, consecutive.
  int bid = blockIdx.x;
  int xcd = bid & 7, jj = bid >> 3;
  int bh = (xcd << 3) + (jj >> 4), qb = jj & 15;
  int b = bh >> 4, h = bh & 15;
  int q0 = qb << 6;
  int tid = threadIdx.x, lane = tid & 63, wave = tid >> 6;
  int l15 = lane & 15, lhi = lane >> 4;

  // Q fragments in registers
  int qrow = q0 + (wave << 4) + l15;
  v8s aq[2];
  #pragma unroll
  for (int ks = 0; ks < 2; ks++)
    aq[ks] = *(const v8s*)&Qall[(size_t)((b << 10) + qrow)*1024 + (h << 6) + (ks << 5) + (lhi << 3)];

  // window-staging pair constants: 576 = 64 rows x 9 chunks per table
  int prow_[3], pcc_[3]; bool pval[3];
  #pragma unroll
  for (int u = 0; u < 3; u++){
    int pp = tid + (u << 8);
    pval[u] = pp < 576;
    prow_[u] = pp / 9; pcc_[u] = pp - prow_[u]*9;
  }
  const size_t cbase0 = ((size_t)((b << 10) + q0))*8192 + (h << 9);
  const size_t pbase0 = ((size_t)(b << 10))*8192 + (h << 9);

  v8s kst[2], vst[2], cst[3], pst[3];
  bool okc[3], okp[3];
  unsigned short bc_st[3], bp_st[3];
  unsigned long long t64st[4];

  auto issue = [&](int kt){
    int k0 = kt << 6;
    // packed idx words for this tile's bias add (global, L2-hot)
    int gbase = q0 - k0 + (wave << 4) + (lhi << 2) + 1023;
    #pragma unroll
    for (int j = 0; j < 4; j++) t64st[j] = t64g[gbase - (j << 4) - l15];
    #pragma unroll
    for (int u = 0; u < 2; u++){
      int ch = tid + (u << 8);
      int rr = ch >> 3, seg = ch & 7;
      kst[u] = *(const v8s*)&Kall[(size_t)((b << 10) + k0 + rr)*1024 + (h << 6) + (seg << 3)];
      vst[u] = *(const v8s*)&Vt  [(size_t)((b << 10) + (h << 6) + rr)*1024 + k0 + (seg << 3)];
    }
    #pragma unroll
    for (int u = 0; u < 3; u++){
      okc[u] = okp[u] = false;
      if (pval[u]){
        int row = prow_[u], cc = pcc_[u];
        // cw (q-row): window bounds from global idx table (L2-hot)
        int ilo = idxt[q0 + row - k0 + 960];
        int ihi = idxt[q0 + row - k0 + 1023];
        int bc = ilo & ~7;
        bc_st[u] = (unsigned short)bc;
        okc[u] = cc <= ((ihi - bc) >> 3);
        if (okc[u]) cst[u] = *(const v8s*)&c2p[cbase0 + (size_t)row*8192 + bc + (cc << 3)];
        // pw (k-row)
        int ilop = idxt[q0 + 1023 - k0 - row];
        int ihip = idxt[q0 + 1086 - k0 - row];
        int bp = ilop & ~7;
        bp_st[u] = (unsigned short)bp;
        okp[u] = cc <= ((ihip - bp) >> 3);
        if (okp[u]) pst[u] = *(const v8s*)&p2c[pbase0 + (size_t)(k0 + row)*8192 + bp + (cc << 3)];
      }
    }
  };

  v4f o_acc[4] = {};
  float m_run[4], l_part[4];
  #pragma unroll
  for (int r = 0; r < 4; r++){ m_run[r] = -INFINITY; l_part[r] = 0.f; }

  issue(0);

  int prb[4];
  #pragma unroll
  for (int j = 0; j < 4; j++) prb[j] = ((j << 4) + l15) * 72;

  for (int kt = 0; kt < 16; kt++){
    __syncthreads();          // prior-iter LDS readers done
    // K/V writes (XOR swizzle)
    #pragma unroll
    for (int u = 0; u < 2; u++){
      int ch = tid + (u << 8);
      int rr = ch >> 3, seg = ch & 7;
      *(v8s*)&k_lds[rr*64 + ((seg ^ (rr & 7)) << 3)] = kst[u];
      *(v8s*)&v_lds[rr*64 + ((seg ^ (rr & 7)) << 3)] = vst[u];
    }
    // window writes + per-row bases
    #pragma unroll
    for (int u = 0; u < 3; u++){
      if (pval[u]){
        int row = prow_[u], cc = pcc_[u];
        if (cc == 0){ ws8c[row] = bc_st[u]; ws8p[row] = bp_st[u]; }
        if (okc[u]) *(v8s*)&cw[row*72 + (cc << 3)] = cst[u];
        if (okp[u]) *(v8s*)&pw[row*72 + (cc << 3)] = pst[u];
      }
    }
    // keep this tile's idx words before prefetch overwrites them
    unsigned long long t64u[4];
    #pragma unroll
    for (int j = 0; j < 4; j++) t64u[j] = t64st[j];
    __syncthreads();          // staging visible
    if (kt < 15) issue(kt + 1);   // prefetch next tile (overlaps compute)

    // QK^T
    v4f s_acc[4] = {};
    #pragma unroll
    for (int j = 0; j < 4; j++){
      int krow = (j << 4) + l15;
      #pragma unroll
      for (int ks = 0; ks < 2; ks++){
        v8s bfr = *(const v8s*)&k_lds[krow*64 + ((((ks << 2) + lhi) ^ (krow & 7)) << 3)];
        s_acc[j] = __builtin_amdgcn_mfma_f32_16x16x32_bf16(aq[ks], bfr, s_acc[j], 0, 0, 0);
      }
    }
    // bias add: ids from prefetched packed words, windows from LDS
    v4sh bcv = *(const v4sh*)&ws8c[(wave << 4) + (lhi << 2)];
    int crb[4];
    #pragma unroll
    for (int r = 0; r < 4; r++)
      crb[r] = ((wave << 4) + (lhi << 2) + r) * 72 - (int)(unsigned short)bcv[r];
    #pragma unroll
    for (int j = 0; j < 4; j++){
      int bpj = prb[j] - (int)ws8p[(j << 4) + l15];
      unsigned long long w = t64u[j];
      #pragma unroll
      for (int r = 0; r < 4; r++){
        int id = (int)((w >> (r << 4)) & 0xFFFF);
        s_acc[j][r] += b2f(cw[crb[r] + id]) + b2f(pw[bpj + id]);
      }
    }
    // defer-max online softmax (THR=6): shuffles only on rare trigger
    float lmax[4];
    bool grow = false;
    #pragma unroll
    for (int r = 0; r < 4; r++){
      lmax[r] = fmaxf(fmaxf(s_acc[0][r], s_acc[1][r]), fmaxf(s_acc[2][r], s_acc[3][r]));
      grow |= (lmax[r] > m_run[r] + 6.f);
    }
    if (__any(grow)){
      #pragma unroll
      for (int r = 0; r < 4; r++){
        float mx = lmax[r];
        mx = fmaxf(mx, __shfl_xor(mx, 1));
        mx = fmaxf(mx, __shfl_xor(mx, 2));
        mx = fmaxf(mx, __shfl_xor(mx, 4));
        mx = fmaxf(mx, __shfl_xor(mx, 8));
        float mnew = fmaxf(m_run[r], mx);
        float corr = exp2f(m_run[r] - mnew);
        m_run[r] = mnew;
        l_part[r] *= corr;
        #pragma unroll
        for (int j = 0; j < 4; j++) o_acc[j][r] *= corr;
      }
    }
    // P -> overlay into cw (own-wave rows only; program-ordered within wave)
    #pragma unroll
    for (int r = 0; r < 4; r++){
      int prow = (wave << 4) + (lhi << 2) + r;
      float ps = 0.f;
      #pragma unroll
      for (int j = 0; j < 4; j++){
        float p = exp2f(s_acc[j][r] - m_run[r]);
        ps += p;
        cw[prow*72 + (((j << 4) + l15) ^ ((prow & 7) << 3))] = f2b(p);
      }
      l_part[r] += ps;          // per-lane partial; reduced once at the end
    }
    // PV (same-wave P rows from cw overlay)
    int parow = (wave << 4) + l15;
    #pragma unroll
    for (int ks = 0; ks < 2; ks++){
      v8s pa = *(const v8s*)&cw[parow*72 + ((((ks << 2) + lhi) ^ (parow & 7)) << 3)];
      #pragma unroll
      for (int j = 0; j < 4; j++){
        int vrow = (j << 4) + l15;
        v8s vb = *(const v8s*)&v_lds[vrow*64 + ((((ks << 2) + lhi) ^ (vrow & 7)) << 3)];
        o_acc[j] = __builtin_amdgcn_mfma_f32_16x16x32_bf16(pa, vb, o_acc[j], 0, 0, 0);
      }
    }
  }
  // epilogue: reduce l partials across the 16 lanes of each row, store
  #pragma unroll
  for (int r = 0; r < 4; r++){
    float ls = l_part[r];
    ls += __shfl_xor(ls, 1); ls += __shfl_xor(ls, 2);
    ls += __shfl_xor(ls, 4); ls += __shfl_xor(ls, 8);
    int row = q0 + (wave << 4) + (lhi << 2) + r;
    float inv = 1.f / ls;
    #pragma unroll
    for (int j = 0; j < 4; j++)
      out[(size_t)((b << 10) + row)*1024 + (h << 6) + (j << 4) + l15] = o_acc[j][r] * inv;
  }
}

// ---------------------------------------------------------------------------
extern "C" void kernel_launch(void* const* d_in, const int* in_sizes, int n_in,
                              void* d_out, int out_size, void* d_ws, size_t ws_size,
                              hipStream_t stream)
{
  const float* hs  = (const float*)d_in[0];
  const float* rel = (const float*)d_in[1];
  const float* Wq  = (const float*)d_in[2];
  const float* bq  = (const float*)d_in[3];
  const float* Wk  = (const float*)d_in[4];
  const float* bk  = (const float*)d_in[5];
  const float* Wv  = (const float*)d_in[6];
  const float* bv  = (const float*)d_in[7];
  float* out = (float*)d_out;

  char* ws = (char*)d_ws;
  size_t off = 0;
  auto alloc = [&](size_t bytes) -> void* {
    void* p = ws + off; off += (bytes + 255) & ~(size_t)255; return p;
  };
  short*              idxt  = (short*)             alloc(2047 * 2);
  unsigned long long* tab64 = (unsigned long long*)alloc(2056 * 8);
  unsigned short* Xb   = (unsigned short*)alloc((size_t)4608*1024*2);
  unsigned short* Wt3  = (unsigned short*)alloc((size_t)3072*1024*2);
  unsigned short* Qa   = (unsigned short*)alloc((size_t)4608*1024*2);
  unsigned short* Ka   = (unsigned short*)alloc((size_t)4608*1024*2);
  unsigned short* Va   = (unsigned short*)alloc((size_t)4608*1024*2);
  unsigned short* VtT  = (unsigned short*)alloc((size_t)4096*1024*2);
  unsigned short* C2P  = (unsigned short*)alloc((size_t)4096*8192*2);
  unsigned short* P2C  = (unsigned short*)alloc((size_t)4096*8192*2);
  (void)                                  alloc(4096);   // OOB-read pad
  (void)ws_size; (void)in_sizes; (void)n_in; (void)out_size;

  pack_x<<<2313, 256, 0, stream>>>(hs, rel, Xb, idxt, tab64);
  transp3<<<dim3(256, 3), 256, 0, stream>>>(Wq, Wk, Wv, Wt3);

  const float alpha_q = 1.4426950408889634f / sqrtf(192.f);  // log2(e)/sqrt(D*3)
  gemm_qkv<<<864, 256, 0, stream>>>(Xb, Wt3, Qa, Ka, Va, bq, bk, bv, alpha_q);

  transp_b<<<dim3(256, 1, 4), 256, 0, stream>>>(Va, VtT);

  gemm_pos<<<dim3(128, 32), 256, 0, stream>>>(Qa, Ka, C2P, P2C);

  attn<<<1024, 256, 0, stream>>>(Qa, Ka, VtT, C2P, P2C, idxt, tab64, out);
}

// Round 6
// 221.612 us; speedup vs baseline: 2.1718x; 2.1718x over previous
//
#include <hip/hip_runtime.h>
#include <hip/hip_bf16.h>
#include <math.h>

typedef __attribute__((ext_vector_type(8))) short v8s;   // 8 x bf16 (4 VGPR)
typedef __attribute__((ext_vector_type(4))) short v4sh;  // 4 x bf16
typedef __attribute__((ext_vector_type(4))) float v4f;   // MFMA acc

#define AS1(p) ((const __attribute__((address_space(1))) void*)(p))
#define AS3(p) ((__attribute__((address_space(3))) void*)(p))

__device__ inline unsigned short f2b(float f){
  __hip_bfloat16 h = __float2bfloat16(f);
  return __builtin_bit_cast(unsigned short, h);
}
__device__ inline float b2f(unsigned short u){
  __hip_bfloat16 h = __builtin_bit_cast(__hip_bfloat16, u);
  return __bfloat162float(h);
}

// id(table index i), delta = i - 1023
__device__ inline int bucket_id(int i){
  int r = i - 1023;
  if (r > 511) r = 511; if (r < -511) r = -511;
  float sign = (r > 0) ? 1.f : ((r < 0) ? -1.f : 0.f);
  int ap = r < 0 ? -r : r; if (ap < 1) ap = 1;
  float bucket;
  if (ap < 128) bucket = (float)ap * sign;
  else {
    float lp = ceilf(logf((float)ap / 128.f) / logf(511.f/128.f) * 127.f) + 128.f;
    bucket = lp * sign;
  }
  int idx = (int)bucket + 256;
  if (idx < 0) idx = 0; if (idx > 511) idx = 511;
  return idx;
}

// ------- prep: f32 -> bf16 pack of [hidden ; rel] + idx tables tail --------
__global__ __launch_bounds__(256) void pack_x(const float* __restrict__ hs,
                                              const float* __restrict__ rel,
                                              unsigned short* __restrict__ X,
                                              short* __restrict__ tab,
                                              unsigned long long* __restrict__ tab64){
  int blk = blockIdx.x;
  if (blk >= 2304){
    int i = (blk - 2304)*256 + threadIdx.x;
    if (i < 2047) tab[i] = (short)bucket_id(i);
    if (i < 2056){
      unsigned long long w = 0;
      #pragma unroll
      for (int r = 0; r < 4; r++)
        w |= (unsigned long long)(unsigned short)bucket_id(i + r) << (16*r);
      tab64[i] = w;
    }
    return;
  }
  const int HT8 = 4096*1024/8;
  int i8 = blk*256 + threadIdx.x;
  const float* src = (i8 < HT8) ? (hs + (size_t)i8*8) : (rel + ((size_t)i8 - HT8)*8);
  v8s o;
  #pragma unroll
  for (int j = 0; j < 8; j++) o[j] = (short)f2b(src[j]);
  *(v8s*)&X[(size_t)i8*8] = o;
}

// ---------------- transpose f32 -> bf16, all three weights -----------------
__global__ __launch_bounds__(256) void transp3(const float* __restrict__ Wq,
                                               const float* __restrict__ Wk,
                                               const float* __restrict__ Wv,
                                               unsigned short* __restrict__ out){
  __shared__ unsigned short t[64][65];
  const float* in = (blockIdx.y == 0) ? Wq : ((blockIdx.y == 1) ? Wk : Wv);
  out += (size_t)blockIdx.y << 20;
  int r0 = (blockIdx.x >> 4) << 6, c0 = (blockIdx.x & 15) << 6;
  int tx = threadIdx.x & 63, ty = threadIdx.x >> 6;
  #pragma unroll
  for (int p = 0; p < 16; p++){ int r = (p<<2)+ty; t[tx][r] = f2b(in[(size_t)(r0+r)*1024 + c0+tx]); }
  __syncthreads();
  #pragma unroll
  for (int p = 0; p < 16; p++){ int c = (p<<2)+ty; out[(size_t)(c0+c)*1024 + r0+tx] = t[c][tx]; }
}

// ---------------- transpose bf16 1024x1024 per batch (V -> V^T) ------------
__global__ __launch_bounds__(256) void transp_b(const unsigned short* __restrict__ in,
                                                unsigned short* __restrict__ out){
  __shared__ unsigned short t[64][65];
  size_t base = (size_t)blockIdx.z << 20;
  int r0 = (blockIdx.x >> 4) << 6, c0 = (blockIdx.x & 15) << 6;
  int tx = threadIdx.x & 63, ty = threadIdx.x >> 6;
  #pragma unroll
  for (int p = 0; p < 16; p++){ int r = (p<<2)+ty; t[tx][r] = in[base + (size_t)(r0+r)*1024 + c0+tx]; }
  __syncthreads();
  #pragma unroll
  for (int p = 0; p < 16; p++){ int c = (p<<2)+ty; out[base + (size_t)(c0+c)*1024 + r0+tx] = t[c][tx]; }
}

// ---------------- merged QKV GEMM: [Xb 4608x1024] @ [Wt3 3072x1024]^T ------
__global__ __launch_bounds__(256) void gemm_qkv(
    const unsigned short* __restrict__ A,    // [4608][1024]
    const unsigned short* __restrict__ Bt3,  // [3072][1024] rows = out cols
    unsigned short* __restrict__ Qa, unsigned short* __restrict__ Ka,
    unsigned short* __restrict__ Va,
    const float* __restrict__ bq, const float* __restrict__ bk,
    const float* __restrict__ bv, float alpha_q)
{
  __shared__ unsigned short a_tile[128*64];
  __shared__ unsigned short b_tile[128*64];
  int nb = (blockIdx.x & 7)*108 + (blockIdx.x >> 3);   // XCD swizzle (864 = 8*108)
  int bm = nb / 24, bn = nb % 24;
  int m0 = bm << 7, n0 = bn << 7;
  int tid = threadIdx.x, lane = tid & 63, wave = tid >> 6;
  int l15 = lane & 15, lhi = lane >> 4;
  int rbase = (wave >> 1) << 6, cbase = (wave & 1) << 6;
  int crow[4], csw[4];
  #pragma unroll
  for (int u = 0; u < 4; u++){
    int ch = tid + (u << 8);
    crow[u] = ch >> 3;
    csw[u] = ((ch & 7) ^ (crow[u] & 7)) << 3;
  }
  v4f acc[4][4] = {};
  for (int kt = 0; kt < 1024; kt += 64){
    #pragma unroll
    for (int u = 0; u < 4; u++){
      int ch = tid + (u << 8);
      __builtin_amdgcn_global_load_lds(AS1(A   + (size_t)(m0 + crow[u])*1024 + kt + csw[u]),
                                       AS3(a_tile + (size_t)ch*8), 16, 0, 0);
      __builtin_amdgcn_global_load_lds(AS1(Bt3 + (size_t)(n0 + crow[u])*1024 + kt + csw[u]),
                                       AS3(b_tile + (size_t)ch*8), 16, 0, 0);
    }
    __syncthreads();
    #pragma unroll
    for (int ks = 0; ks < 2; ks++){
      v8s af[4], bfr[4];
      int kb = (ks << 2) + lhi;
      #pragma unroll
      for (int i = 0; i < 4; i++){
        int r = rbase + (i << 4) + l15;
        af[i] = *(const v8s*)&a_tile[r*64 + ((kb ^ (r & 7)) << 3)];
      }
      #pragma unroll
      for (int j = 0; j < 4; j++){
        int r = cbase + (j << 4) + l15;
        bfr[j] = *(const v8s*)&b_tile[r*64 + ((kb ^ (r & 7)) << 3)];
      }
      #pragma unroll
      for (int i = 0; i < 4; i++)
        #pragma unroll
        for (int j = 0; j < 4; j++)
          acc[i][j] = __builtin_amdgcn_mfma_f32_16x16x32_bf16(af[i], bfr[j], acc[i][j], 0, 0, 0);
    }
    __syncthreads();
  }
  int seg = n0 >> 10;
  unsigned short* C = (seg == 0) ? Qa : ((seg == 1) ? Ka : Va);
  const float* bias = (seg == 0) ? bq : ((seg == 1) ? bk : bv);
  float alpha = (seg == 0) ? alpha_q : 1.f;
  int nn0 = n0 & 1023;
  #pragma unroll
  for (int i = 0; i < 4; i++){
    int row = m0 + rbase + (i << 4) + (lhi << 2);
    #pragma unroll
    for (int j = 0; j < 4; j++){
      int col = nn0 + cbase + (j << 4) + l15;
      float bvv = bias[col];
      #pragma unroll
      for (int r = 0; r < 4; r++)
        C[(size_t)(row + r)*1024 + col] = f2b((acc[i][j][r] + bvv) * alpha);
    }
  }
}

// ---------------- merged pos GEMMs: c2p & p2c, K=64, per head --------------
__global__ __launch_bounds__(256) void gemm_pos(
    const unsigned short* __restrict__ Qa,   // [4608][1024] (scaled)
    const unsigned short* __restrict__ Ka,   // [4608][1024]
    unsigned short* __restrict__ C2P,        // [4096][8192]
    unsigned short* __restrict__ P2C)        // [4096][8192]
{
  __shared__ unsigned short a_tile[128*64];
  __shared__ unsigned short b_tile[128*64];
  int tab = blockIdx.y >> 4, h = blockIdx.y & 15;
  int bm = blockIdx.x >> 2, bn = blockIdx.x & 3;
  int m0 = bm << 7, n0 = bn << 7;
  const unsigned short* A  = tab ? Ka : Qa;
  const unsigned short* Bt = tab ? Qa : Ka;
  unsigned short* C = tab ? P2C : C2P;
  int tid = threadIdx.x, lane = tid & 63, wave = tid >> 6;
  int l15 = lane & 15, lhi = lane >> 4;
  int rbase = (wave >> 1) << 6, cbase = (wave & 1) << 6;
  #pragma unroll
  for (int u = 0; u < 4; u++){
    int ch = tid + (u << 8);
    int row = ch >> 3;
    int csw = ((ch & 7) ^ (row & 7)) << 3;
    __builtin_amdgcn_global_load_lds(AS1(A  + (size_t)(m0 + row)*1024 + (h << 6) + csw),
                                     AS3(a_tile + (size_t)ch*8), 16, 0, 0);
    __builtin_amdgcn_global_load_lds(AS1(Bt + (size_t)(4096 + n0 + row)*1024 + (h << 6) + csw),
                                     AS3(b_tile + (size_t)ch*8), 16, 0, 0);
  }
  __syncthreads();
  v4f acc[4][4] = {};
  #pragma unroll
  for (int ks = 0; ks < 2; ks++){
    v8s af[4], bfr[4];
    int kb = (ks << 2) + lhi;
    #pragma unroll
    for (int i = 0; i < 4; i++){
      int r = rbase + (i << 4) + l15;
      af[i] = *(const v8s*)&a_tile[r*64 + ((kb ^ (r & 7)) << 3)];
    }
    #pragma unroll
    for (int j = 0; j < 4; j++){
      int r = cbase + (j << 4) + l15;
      bfr[j] = *(const v8s*)&b_tile[r*64 + ((kb ^ (r & 7)) << 3)];
    }
    #pragma unroll
    for (int i = 0; i < 4; i++)
      #pragma unroll
      for (int j = 0; j < 4; j++)
        acc[i][j] = __builtin_amdgcn_mfma_f32_16x16x32_bf16(af[i], bfr[j], acc[i][j], 0, 0, 0);
  }
  #pragma unroll
  for (int i = 0; i < 4; i++){
    int row = m0 + rbase + (i << 4) + (lhi << 2);
    #pragma unroll
    for (int j = 0; j < 4; j++){
      int col = n0 + cbase + (j << 4) + l15;
      #pragma unroll
      for (int r = 0; r < 4; r++)
        C[(size_t)(row + r)*8192 + (h << 9) + col] = f2b(acc[i][j][r]);
    }
  }
}

// ---------------- fused disentangled flash attention -----------------------
// 1024 blocks (XCD-swizzled), 256 thr = 4 waves, 64 q rows/block.
// LDS 34.5 KB -> 4 blocks/CU by LDS; VGPR left to the compiler (128 in r4,
// = 4 waves/SIMD). NO launch_bounds min-occupancy (r5 spill bomb).
__global__ __launch_bounds__(256) void attn(
  const unsigned short* __restrict__ Qall,   // [4608][1024] (scaled by log2e/sqrt(192))
  const unsigned short* __restrict__ Kall,   // [4608][1024]
  const unsigned short* __restrict__ Vt,     // [4096][1024]: row=b*1024+h*64+d, col=s
  const unsigned short* __restrict__ c2p,    // [4096][8192]
  const unsigned short* __restrict__ p2c,    // [4096][8192]
  const short* __restrict__ idxt,            // [2047]
  const unsigned long long* __restrict__ t64g, // [2056] packed ids i..i+3
  float* __restrict__ out)                   // [4][1024][1024] f32
{
  __shared__ unsigned short k_lds[64*64];    // 8 KB
  __shared__ unsigned short v_lds[64*64];    // 8 KB
  __shared__ unsigned short cw[64*72];       // 9 KB   c2p windows; P overlaid per-wave
  __shared__ unsigned short pw[64*72];       // 9 KB   p2c windows
  __shared__ unsigned short ws8c[64];        // per-row window bases (q rows)
  __shared__ unsigned short ws8p[64];        // per-row window bases (k rows)

  // XCD-aware swizzle: all 16 q-blocks of one (b,h) on one XCD, consecutive.
  int bid = blockIdx.x;
  int xcd = bid & 7, jj = bid >> 3;
  int bh = (xcd << 3) + (jj >> 4), qb = jj & 15;
  int b = bh >> 4, h = bh & 15;
  int q0 = qb << 6;
  int tid = threadIdx.x, lane = tid & 63, wave = tid >> 6;
  int l15 = lane & 15, lhi = lane >> 4;

  // Q fragments in registers
  int qrow = q0 + (wave << 4) + l15;
  v8s aq[2];
  #pragma unroll
  for (int ks = 0; ks < 2; ks++)
    aq[ks] = *(const v8s*)&Qall[(size_t)((b << 10) + qrow)*1024 + (h << 6) + (ks << 5) + (lhi << 3)];

  // window-staging pair constants: 576 = 64 rows x 9 chunks per table
  int prow_[3], pcc_[3]; bool pval[3];
  #pragma unroll
  for (int u = 0; u < 3; u++){
    int pp = tid + (u << 8);
    pval[u] = pp < 576;
    prow_[u] = pp / 9; pcc_[u] = pp - prow_[u]*9;
  }
  const size_t cbase0 = ((size_t)((b << 10) + q0))*8192 + (h << 9);
  const size_t pbase0 = ((size_t)(b << 10))*8192 + (h << 9);

  v8s kst[2], vst[2], cst[3], pst[3];
  bool okc[3], okp[3];
  unsigned short bc_st[3], bp_st[3];
  unsigned long long t64st[4];

  auto issue = [&](int kt){
    int k0 = kt << 6;
    // packed idx words for this tile's bias add (global, L2-hot)
    int gbase = q0 - k0 + (wave << 4) + (lhi << 2) + 1023;
    #pragma unroll
    for (int j = 0; j < 4; j++) t64st[j] = t64g[gbase - (j << 4) - l15];
    #pragma unroll
    for (int u = 0; u < 2; u++){
      int ch = tid + (u << 8);
      int rr = ch >> 3, seg = ch & 7;
      kst[u] = *(const v8s*)&Kall[(size_t)((b << 10) + k0 + rr)*1024 + (h << 6) + (seg << 3)];
      vst[u] = *(const v8s*)&Vt  [(size_t)((b << 10) + (h << 6) + rr)*1024 + k0 + (seg << 3)];
    }
    #pragma unroll
    for (int u = 0; u < 3; u++){
      okc[u] = okp[u] = false;
      if (pval[u]){
        int row = prow_[u], cc = pcc_[u];
        // cw (q-row): window bounds from global idx table (L2-hot)
        int ilo = idxt[q0 + row - k0 + 960];
        int ihi = idxt[q0 + row - k0 + 1023];
        int bc = ilo & ~7;
        bc_st[u] = (unsigned short)bc;
        okc[u] = cc <= ((ihi - bc) >> 3);
        if (okc[u]) cst[u] = *(const v8s*)&c2p[cbase0 + (size_t)row*8192 + bc + (cc << 3)];
        // pw (k-row)
        int ilop = idxt[q0 + 1023 - k0 - row];
        int ihip = idxt[q0 + 1086 - k0 - row];
        int bp = ilop & ~7;
        bp_st[u] = (unsigned short)bp;
        okp[u] = cc <= ((ihip - bp) >> 3);
        if (okp[u]) pst[u] = *(const v8s*)&p2c[pbase0 + (size_t)(k0 + row)*8192 + bp + (cc << 3)];
      }
    }
  };

  v4f o_acc[4] = {};
  float m_run[4], l_part[4];
  #pragma unroll
  for (int r = 0; r < 4; r++){ m_run[r] = -INFINITY; l_part[r] = 0.f; }

  issue(0);

  int prb[4];
  #pragma unroll
  for (int j = 0; j < 4; j++) prb[j] = ((j << 4) + l15) * 72;

  for (int kt = 0; kt < 16; kt++){
    __syncthreads();          // prior-iter LDS readers done
    // K/V writes (XOR swizzle)
    #pragma unroll
    for (int u = 0; u < 2; u++){
      int ch = tid + (u << 8);
      int rr = ch >> 3, seg = ch & 7;
      *(v8s*)&k_lds[rr*64 + ((seg ^ (rr & 7)) << 3)] = kst[u];
      *(v8s*)&v_lds[rr*64 + ((seg ^ (rr & 7)) << 3)] = vst[u];
    }
    // window writes + per-row bases
    #pragma unroll
    for (int u = 0; u < 3; u++){
      if (pval[u]){
        int row = prow_[u], cc = pcc_[u];
        if (cc == 0){ ws8c[row] = bc_st[u]; ws8p[row] = bp_st[u]; }
        if (okc[u]) *(v8s*)&cw[row*72 + (cc << 3)] = cst[u];
        if (okp[u]) *(v8s*)&pw[row*72 + (cc << 3)] = pst[u];
      }
    }
    // keep this tile's idx words before prefetch overwrites them
    unsigned long long t64u[4];
    #pragma unroll
    for (int j = 0; j < 4; j++) t64u[j] = t64st[j];
    __syncthreads();          // staging visible
    if (kt < 15) issue(kt + 1);   // prefetch next tile (overlaps compute)

    // QK^T
    v4f s_acc[4] = {};
    #pragma unroll
    for (int j = 0; j < 4; j++){
      int krow = (j << 4) + l15;
      #pragma unroll
      for (int ks = 0; ks < 2; ks++){
        v8s bfr = *(const v8s*)&k_lds[krow*64 + ((((ks << 2) + lhi) ^ (krow & 7)) << 3)];
        s_acc[j] = __builtin_amdgcn_mfma_f32_16x16x32_bf16(aq[ks], bfr, s_acc[j], 0, 0, 0);
      }
    }
    // bias add: ids from prefetched packed words, windows from LDS
    v4sh bcv = *(const v4sh*)&ws8c[(wave << 4) + (lhi << 2)];
    int crb[4];
    #pragma unroll
    for (int r = 0; r < 4; r++)
      crb[r] = ((wave << 4) + (lhi << 2) + r) * 72 - (int)(unsigned short)bcv[r];
    #pragma unroll
    for (int j = 0; j < 4; j++){
      int bpj = prb[j] - (int)ws8p[(j << 4) + l15];
      unsigned long long w = t64u[j];
      #pragma unroll
      for (int r = 0; r < 4; r++){
        int id = (int)((w >> (r << 4)) & 0xFFFF);
        s_acc[j][r] += b2f(cw[crb[r] + id]) + b2f(pw[bpj + id]);
      }
    }
    // defer-max online softmax (THR=6): shuffles only on rare trigger
    float lmax[4];
    bool grow = false;
    #pragma unroll
    for (int r = 0; r < 4; r++){
      lmax[r] = fmaxf(fmaxf(s_acc[0][r], s_acc[1][r]), fmaxf(s_acc[2][r], s_acc[3][r]));
      grow |= (lmax[r] > m_run[r] + 6.f);
    }
    if (__any(grow)){
      #pragma unroll
      for (int r = 0; r < 4; r++){
        float mx = lmax[r];
        mx = fmaxf(mx, __shfl_xor(mx, 1));
        mx = fmaxf(mx, __shfl_xor(mx, 2));
        mx = fmaxf(mx, __shfl_xor(mx, 4));
        mx = fmaxf(mx, __shfl_xor(mx, 8));
        float mnew = fmaxf(m_run[r], mx);
        float corr = exp2f(m_run[r] - mnew);
        m_run[r] = mnew;
        l_part[r] *= corr;
        #pragma unroll
        for (int j = 0; j < 4; j++) o_acc[j][r] *= corr;
      }
    }
    // P -> overlay into cw (own-wave rows only; program-ordered within wave)
    #pragma unroll
    for (int r = 0; r < 4; r++){
      int prow = (wave << 4) + (lhi << 2) + r;
      float ps = 0.f;
      #pragma unroll
      for (int j = 0; j < 4; j++){
        float p = exp2f(s_acc[j][r] - m_run[r]);
        ps += p;
        cw[prow*72 + (((j << 4) + l15) ^ ((prow & 7) << 3))] = f2b(p);
      }
      l_part[r] += ps;          // per-lane partial; reduced once at the end
    }
    // PV (same-wave P rows from cw overlay)
    int parow = (wave << 4) + l15;
    #pragma unroll
    for (int ks = 0; ks < 2; ks++){
      v8s pa = *(const v8s*)&cw[parow*72 + ((((ks << 2) + lhi) ^ (parow & 7)) << 3)];
      #pragma unroll
      for (int j = 0; j < 4; j++){
        int vrow = (j << 4) + l15;
        v8s vb = *(const v8s*)&v_lds[vrow*64 + ((((ks << 2) + lhi) ^ (vrow & 7)) << 3)];
        o_acc[j] = __builtin_amdgcn_mfma_f32_16x16x32_bf16(pa, vb, o_acc[j], 0, 0, 0);
      }
    }
  }
  // epilogue: reduce l partials across the 16 lanes of each row, store
  #pragma unroll
  for (int r = 0; r < 4; r++){
    float ls = l_part[r];
    ls += __shfl_xor(ls, 1); ls += __shfl_xor(ls, 2);
    ls += __shfl_xor(ls, 4); ls += __shfl_xor(ls, 8);
    int row = q0 + (wave << 4) + (lhi << 2) + r;
    float inv = 1.f / ls;
    #pragma unroll
    for (int j = 0; j < 4; j++)
      out[(size_t)((b << 10) + row)*1024 + (h << 6) + (j << 4) + l15] = o_acc[j][r] * inv;
  }
}

// ---------------------------------------------------------------------------
extern "C" void kernel_launch(void* const* d_in, const int* in_sizes, int n_in,
                              void* d_out, int out_size, void* d_ws, size_t ws_size,
                              hipStream_t stream)
{
  const float* hs  = (const float*)d_in[0];
  const float* rel = (const float*)d_in[1];
  const float* Wq  = (const float*)d_in[2];
  const float* bq  = (const float*)d_in[3];
  const float* Wk  = (const float*)d_in[4];
  const float* bk  = (const float*)d_in[5];
  const float* Wv  = (const float*)d_in[6];
  const float* bv  = (const float*)d_in[7];
  float* out = (float*)d_out;

  char* ws = (char*)d_ws;
  size_t off = 0;
  auto alloc = [&](size_t bytes) -> void* {
    void* p = ws + off; off += (bytes + 255) & ~(size_t)255; return p;
  };
  short*              idxt  = (short*)             alloc(2047 * 2);
  unsigned long long* tab64 = (unsigned long long*)alloc(2056 * 8);
  unsigned short* Xb   = (unsigned short*)alloc((size_t)4608*1024*2);
  unsigned short* Wt3  = (unsigned short*)alloc((size_t)3072*1024*2);
  unsigned short* Qa   = (unsigned short*)alloc((size_t)4608*1024*2);
  unsigned short* Ka   = (unsigned short*)alloc((size_t)4608*1024*2);
  unsigned short* Va   = (unsigned short*)alloc((size_t)4608*1024*2);
  unsigned short* VtT  = (unsigned short*)alloc((size_t)4096*1024*2);
  unsigned short* C2P  = (unsigned short*)alloc((size_t)4096*8192*2);
  unsigned short* P2C  = (unsigned short*)alloc((size_t)4096*8192*2);
  (void)                                  alloc(4096);   // OOB-read pad
  (void)ws_size; (void)in_sizes; (void)n_in; (void)out_size;

  pack_x<<<2313, 256, 0, stream>>>(hs, rel, Xb, idxt, tab64);
  transp3<<<dim3(256, 3), 256, 0, stream>>>(Wq, Wk, Wv, Wt3);

  const float alpha_q = 1.4426950408889634f / sqrtf(192.f);  // log2(e)/sqrt(D*3)
  gemm_qkv<<<864, 256, 0, stream>>>(Xb, Wt3, Qa, Ka, Va, bq, bk, bv, alpha_q);

  transp_b<<<dim3(256, 1, 4), 256, 0, stream>>>(Va, VtT);

  gemm_pos<<<dim3(128, 32), 256, 0, stream>>>(Qa, Ka, C2P, P2C);

  attn<<<1024, 256, 0, stream>>>(Qa, Ka, VtT, C2P, P2C, idxt, tab64, out);
}

// Round 7
// 178.851 us; speedup vs baseline: 2.6911x; 1.2391x over previous
//
#include <hip/hip_runtime.h>
#include <hip/hip_bf16.h>
#include <math.h>

typedef __attribute__((ext_vector_type(8))) short v8s;   // 8 x bf16 (4 VGPR)
typedef __attribute__((ext_vector_type(4))) short v4sh;  // 4 x i16
typedef __attribute__((ext_vector_type(4))) float v4f;   // MFMA acc

#define AS1(p) ((const __attribute__((address_space(1))) void*)(p))
#define AS3(p) ((__attribute__((address_space(3))) void*)(p))

__device__ inline unsigned short f2b(float f){
  __hip_bfloat16 h = __float2bfloat16(f);
  return __builtin_bit_cast(unsigned short, h);
}
__device__ inline float b2f(unsigned short u){
  __hip_bfloat16 h = __builtin_bit_cast(__hip_bfloat16, u);
  return __bfloat162float(h);
}

// id(table index i), delta = i - 1023
__device__ inline int bucket_id(int i){
  int r = i - 1023;
  if (r > 511) r = 511; if (r < -511) r = -511;
  float sign = (r > 0) ? 1.f : ((r < 0) ? -1.f : 0.f);
  int ap = r < 0 ? -r : r; if (ap < 1) ap = 1;
  float bucket;
  if (ap < 128) bucket = (float)ap * sign;
  else {
    float lp = ceilf(logf((float)ap / 128.f) / logf(511.f/128.f) * 127.f) + 128.f;
    bucket = lp * sign;
  }
  int idx = (int)bucket + 256;
  if (idx < 0) idx = 0; if (idx > 511) idx = 511;
  return idx;
}

// ------- prep: f32 -> bf16 pack of [hidden ; rel] + idx tables tail --------
__global__ __launch_bounds__(256) void pack_x(const float* __restrict__ hs,
                                              const float* __restrict__ rel,
                                              unsigned short* __restrict__ X,
                                              short* __restrict__ tab,
                                              unsigned long long* __restrict__ tab64){
  int blk = blockIdx.x;
  if (blk >= 2304){
    int i = (blk - 2304)*256 + threadIdx.x;
    if (i < 2047) tab[i] = (short)bucket_id(i);
    if (i < 2056){
      unsigned long long w = 0;
      #pragma unroll
      for (int r = 0; r < 4; r++)
        w |= (unsigned long long)(unsigned short)bucket_id(i + r) << (16*r);
      tab64[i] = w;
    }
    return;
  }
  const int HT8 = 4096*1024/8;
  int i8 = blk*256 + threadIdx.x;
  const float* src = (i8 < HT8) ? (hs + (size_t)i8*8) : (rel + ((size_t)i8 - HT8)*8);
  v8s o;
  #pragma unroll
  for (int j = 0; j < 8; j++) o[j] = (short)f2b(src[j]);
  *(v8s*)&X[(size_t)i8*8] = o;
}

// ---------------- transpose f32 -> bf16, all three weights -----------------
__global__ __launch_bounds__(256) void transp3(const float* __restrict__ Wq,
                                               const float* __restrict__ Wk,
                                               const float* __restrict__ Wv,
                                               unsigned short* __restrict__ out){
  __shared__ unsigned short t[64][65];
  const float* in = (blockIdx.y == 0) ? Wq : ((blockIdx.y == 1) ? Wk : Wv);
  out += (size_t)blockIdx.y << 20;
  int r0 = (blockIdx.x >> 4) << 6, c0 = (blockIdx.x & 15) << 6;
  int tx = threadIdx.x & 63, ty = threadIdx.x >> 6;
  #pragma unroll
  for (int p = 0; p < 16; p++){ int r = (p<<2)+ty; t[tx][r] = f2b(in[(size_t)(r0+r)*1024 + c0+tx]); }
  __syncthreads();
  #pragma unroll
  for (int p = 0; p < 16; p++){ int c = (p<<2)+ty; out[(size_t)(c0+c)*1024 + r0+tx] = t[c][tx]; }
}

// ---------------- transpose bf16 1024x1024 per batch (V -> V^T) ------------
__global__ __launch_bounds__(256) void transp_b(const unsigned short* __restrict__ in,
                                                unsigned short* __restrict__ out){
  __shared__ unsigned short t[64][65];
  size_t base = (size_t)blockIdx.z << 20;
  int r0 = (blockIdx.x >> 4) << 6, c0 = (blockIdx.x & 15) << 6;
  int tx = threadIdx.x & 63, ty = threadIdx.x >> 6;
  #pragma unroll
  for (int p = 0; p < 16; p++){ int r = (p<<2)+ty; t[tx][r] = in[base + (size_t)(r0+r)*1024 + c0+tx]; }
  __syncthreads();
  #pragma unroll
  for (int p = 0; p < 16; p++){ int c = (p<<2)+ty; out[base + (size_t)(c0+c)*1024 + r0+tx] = t[c][tx]; }
}

// ---------------- merged QKV GEMM: [Xb 4608x1024] @ [Wt3 3072x1024]^T ------
__global__ __launch_bounds__(256) void gemm_qkv(
    const unsigned short* __restrict__ A,    // [4608][1024]
    const unsigned short* __restrict__ Bt3,  // [3072][1024] rows = out cols
    unsigned short* __restrict__ Qa, unsigned short* __restrict__ Ka,
    unsigned short* __restrict__ Va,
    const float* __restrict__ bq, const float* __restrict__ bk,
    const float* __restrict__ bv, float alpha_q)
{
  __shared__ unsigned short a_tile[128*64];
  __shared__ unsigned short b_tile[128*64];
  int nb = (blockIdx.x & 7)*108 + (blockIdx.x >> 3);   // XCD swizzle (864 = 8*108)
  int bm = nb / 24, bn = nb % 24;
  int m0 = bm << 7, n0 = bn << 7;
  int tid = threadIdx.x, lane = tid & 63, wave = tid >> 6;
  int l15 = lane & 15, lhi = lane >> 4;
  int rbase = (wave >> 1) << 6, cbase = (wave & 1) << 6;
  int crow[4], csw[4];
  #pragma unroll
  for (int u = 0; u < 4; u++){
    int ch = tid + (u << 8);
    crow[u] = ch >> 3;
    csw[u] = ((ch & 7) ^ (crow[u] & 7)) << 3;
  }
  v4f acc[4][4] = {};
  for (int kt = 0; kt < 1024; kt += 64){
    #pragma unroll
    for (int u = 0; u < 4; u++){
      int ch = tid + (u << 8);
      __builtin_amdgcn_global_load_lds(AS1(A   + (size_t)(m0 + crow[u])*1024 + kt + csw[u]),
                                       AS3(a_tile + (size_t)ch*8), 16, 0, 0);
      __builtin_amdgcn_global_load_lds(AS1(Bt3 + (size_t)(n0 + crow[u])*1024 + kt + csw[u]),
                                       AS3(b_tile + (size_t)ch*8), 16, 0, 0);
    }
    __syncthreads();
    #pragma unroll
    for (int ks = 0; ks < 2; ks++){
      v8s af[4], bfr[4];
      int kb = (ks << 2) + lhi;
      #pragma unroll
      for (int i = 0; i < 4; i++){
        int r = rbase + (i << 4) + l15;
        af[i] = *(const v8s*)&a_tile[r*64 + ((kb ^ (r & 7)) << 3)];
      }
      #pragma unroll
      for (int j = 0; j < 4; j++){
        int r = cbase + (j << 4) + l15;
        bfr[j] = *(const v8s*)&b_tile[r*64 + ((kb ^ (r & 7)) << 3)];
      }
      #pragma unroll
      for (int i = 0; i < 4; i++)
        #pragma unroll
        for (int j = 0; j < 4; j++)
          acc[i][j] = __builtin_amdgcn_mfma_f32_16x16x32_bf16(af[i], bfr[j], acc[i][j], 0, 0, 0);
    }
    __syncthreads();
  }
  int seg = n0 >> 10;
  unsigned short* C = (seg == 0) ? Qa : ((seg == 1) ? Ka : Va);
  const float* bias = (seg == 0) ? bq : ((seg == 1) ? bk : bv);
  float alpha = (seg == 0) ? alpha_q : 1.f;
  int nn0 = n0 & 1023;
  #pragma unroll
  for (int i = 0; i < 4; i++){
    int row = m0 + rbase + (i << 4) + (lhi << 2);
    #pragma unroll
    for (int j = 0; j < 4; j++){
      int col = nn0 + cbase + (j << 4) + l15;
      float bvv = bias[col];
      #pragma unroll
      for (int r = 0; r < 4; r++)
        C[(size_t)(row + r)*1024 + col] = f2b((acc[i][j][r] + bvv) * alpha);
    }
  }
}

// ---------------- merged pos GEMMs: c2p & p2c, K=64, per head --------------
__global__ __launch_bounds__(256) void gemm_pos(
    const unsigned short* __restrict__ Qa,   // [4608][1024] (scaled)
    const unsigned short* __restrict__ Ka,   // [4608][1024]
    unsigned short* __restrict__ C2P,        // [4096][8192]
    unsigned short* __restrict__ P2C)        // [4096][8192]
{
  __shared__ unsigned short a_tile[128*64];
  __shared__ unsigned short b_tile[128*64];
  int tab = blockIdx.y >> 4, h = blockIdx.y & 15;
  int bm = blockIdx.x >> 2, bn = blockIdx.x & 3;
  int m0 = bm << 7, n0 = bn << 7;
  const unsigned short* A  = tab ? Ka : Qa;
  const unsigned short* Bt = tab ? Qa : Ka;
  unsigned short* C = tab ? P2C : C2P;
  int tid = threadIdx.x, lane = tid & 63, wave = tid >> 6;
  int l15 = lane & 15, lhi = lane >> 4;
  int rbase = (wave >> 1) << 6, cbase = (wave & 1) << 6;
  #pragma unroll
  for (int u = 0; u < 4; u++){
    int ch = tid + (u << 8);
    int row = ch >> 3;
    int csw = ((ch & 7) ^ (row & 7)) << 3;
    __builtin_amdgcn_global_load_lds(AS1(A  + (size_t)(m0 + row)*1024 + (h << 6) + csw),
                                     AS3(a_tile + (size_t)ch*8), 16, 0, 0);
    __builtin_amdgcn_global_load_lds(AS1(Bt + (size_t)(4096 + n0 + row)*1024 + (h << 6) + csw),
                                     AS3(b_tile + (size_t)ch*8), 16, 0, 0);
  }
  __syncthreads();
  v4f acc[4][4] = {};
  #pragma unroll
  for (int ks = 0; ks < 2; ks++){
    v8s af[4], bfr[4];
    int kb = (ks << 2) + lhi;
    #pragma unroll
    for (int i = 0; i < 4; i++){
      int r = rbase + (i << 4) + l15;
      af[i] = *(const v8s*)&a_tile[r*64 + ((kb ^ (r & 7)) << 3)];
    }
    #pragma unroll
    for (int j = 0; j < 4; j++){
      int r = cbase + (j << 4) + l15;
      bfr[j] = *(const v8s*)&b_tile[r*64 + ((kb ^ (r & 7)) << 3)];
    }
    #pragma unroll
    for (int i = 0; i < 4; i++)
      #pragma unroll
      for (int j = 0; j < 4; j++)
        acc[i][j] = __builtin_amdgcn_mfma_f32_16x16x32_bf16(af[i], bfr[j], acc[i][j], 0, 0, 0);
  }
  #pragma unroll
  for (int i = 0; i < 4; i++){
    int row = m0 + rbase + (i << 4) + (lhi << 2);
    #pragma unroll
    for (int j = 0; j < 4; j++){
      int col = n0 + cbase + (j << 4) + l15;
      #pragma unroll
      for (int r = 0; r < 4; r++)
        C[(size_t)(row + r)*8192 + (h << 9) + col] = f2b(acc[i][j][r]);
    }
  }
}

// ---------------- fused disentangled flash attention -----------------------
// 1024 blocks (XCD-swizzled), 256 thr = 4 waves, 64 q rows/block.
// NO register staging: K/V/cw/pw staged via global_load_lds (pre-swizzled
// global source, linear LDS dest). Combined base tables in LDS (4 KB).
// Overlap comes from multi-block residency (m97 pattern), not in-wave
// prefetch -> minimal VGPRs -> 3-4 waves/SIMD.
__global__ __launch_bounds__(256) void attn(
  const unsigned short* __restrict__ Qall,   // [4608][1024] (scaled by log2e/sqrt(192))
  const unsigned short* __restrict__ Kall,   // [4608][1024]
  const unsigned short* __restrict__ Vt,     // [4096][1024]: row=b*1024+h*64+d, col=s
  const unsigned short* __restrict__ c2p,    // [4096][8192]
  const unsigned short* __restrict__ p2c,    // [4096][8192]
  const short* __restrict__ idxt,            // [2047]
  const unsigned long long* __restrict__ t64g, // [2056] packed ids i..i+3
  float* __restrict__ out)                   // [4][1024][1024] f32
{
  __shared__ unsigned short k_lds[64*64];    // 8 KB
  __shared__ unsigned short v_lds[64*64];    // 8 KB
  __shared__ unsigned short cw[64*72];       // 9 KB  c2p windows; P overlaid per-wave
  __shared__ unsigned short pw[64*72];       // 9 KB  p2c windows
  __shared__ short basc[16*64];              // 2 KB  row*72 - bc per (kt,row)
  __shared__ short basp[16*64];              // 2 KB  row*72 - bp per (kt,row)

  // XCD-aware swizzle: all 16 q-blocks of one (b,h) on one XCD, consecutive.
  int bid = blockIdx.x;
  int xcd = bid & 7, jj = bid >> 3;
  int bh = (xcd << 3) + (jj >> 4), qb = jj & 15;
  int b = bh >> 4, h = bh & 15;
  int q0 = qb << 6;
  int tid = threadIdx.x, lane = tid & 63, wave = tid >> 6;
  int l15 = lane & 15, lhi = lane >> 4;

  // ---- one-time: combined window-base tables ----
  #pragma unroll
  for (int v = 0; v < 8; v++){
    int i = tid + (v << 8);
    int kt = (i >> 6) & 15, row = i & 63;
    if (i < 1024){
      int bc = idxt[q0 + row - (kt << 6) + 960] & ~7;
      basc[(kt << 6) + row] = (short)(row*72 - bc);
    } else {
      int bp = idxt[q0 + 1023 - (kt << 6) - row] & ~7;
      basp[(kt << 6) + row] = (short)(row*72 - bp);
    }
  }

  // Q fragments in registers
  int qrow = q0 + (wave << 4) + l15;
  v8s aq[2];
  #pragma unroll
  for (int ks = 0; ks < 2; ks++)
    aq[ks] = *(const v8s*)&Qall[(size_t)((b << 10) + qrow)*1024 + (h << 6) + (ks << 5) + (lhi << 3)];

  // window-staging constants: 576 = 64 rows x 9 chunks per table
  int prow_[3], pcc_[3]; bool pval[3];
  #pragma unroll
  for (int u = 0; u < 3; u++){
    int pp = tid + (u << 8);
    pval[u] = pp < 576;
    prow_[u] = pp / 9; pcc_[u] = pp - prow_[u]*9;
  }
  const size_t cbase0 = ((size_t)((b << 10) + q0))*8192 + (h << 9);
  const size_t pbase0 = ((size_t)(b << 10))*8192 + (h << 9);

  v4f o_acc[4] = {};
  float m_run[4], l_part[4];
  #pragma unroll
  for (int r = 0; r < 4; r++){ m_run[r] = -INFINITY; l_part[r] = 0.f; }

  for (int kt = 0; kt < 16; kt++){
    int k0 = kt << 6;
    __syncthreads();          // prev-tile LDS readers done (iter 0: base tables ready)
    // ---- stage: direct global->LDS, pre-swizzled sources ----
    #pragma unroll
    for (int u = 0; u < 2; u++){
      int ch = tid + (u << 8);
      int rr = ch >> 3, seg = ch & 7;
      int csw = (seg ^ (rr & 7)) << 3;
      __builtin_amdgcn_global_load_lds(AS1(Kall + (size_t)((b << 10) + k0 + rr)*1024 + (h << 6) + csw),
                                       AS3(k_lds + (size_t)ch*8), 16, 0, 0);
      __builtin_amdgcn_global_load_lds(AS1(Vt + (size_t)((b << 10) + (h << 6) + rr)*1024 + k0 + csw),
                                       AS3(v_lds + (size_t)ch*8), 16, 0, 0);
    }
    #pragma unroll
    for (int u = 0; u < 3; u++){
      if (pval[u]){
        int row = prow_[u], cc = pcc_[u];
        int bc = row*72 - (int)basc[(kt << 6) + row];
        __builtin_amdgcn_global_load_lds(AS1(c2p + cbase0 + (size_t)row*8192 + bc + (cc << 3)),
                                         AS3(cw + (size_t)(tid + (u << 8))*8), 16, 0, 0);
        int bp = row*72 - (int)basp[(kt << 6) + row];
        __builtin_amdgcn_global_load_lds(AS1(p2c + pbase0 + (size_t)(k0 + row)*8192 + bp + (cc << 3)),
                                         AS3(pw + (size_t)(tid + (u << 8))*8), 16, 0, 0);
      }
    }
    // packed idx words (complete by the barrier's vmcnt drain)
    unsigned long long t64u[4];
    int gbase = q0 - k0 + (wave << 4) + (lhi << 2) + 1023;
    #pragma unroll
    for (int j = 0; j < 4; j++) t64u[j] = t64g[gbase - (j << 4) - l15];
    __syncthreads();          // staging visible

    // QK^T
    v4f s_acc[4] = {};
    #pragma unroll
    for (int j = 0; j < 4; j++){
      int krow = (j << 4) + l15;
      #pragma unroll
      for (int ks = 0; ks < 2; ks++){
        v8s bfr = *(const v8s*)&k_lds[krow*64 + ((((ks << 2) + lhi) ^ (krow & 7)) << 3)];
        s_acc[j] = __builtin_amdgcn_mfma_f32_16x16x32_bf16(aq[ks], bfr, s_acc[j], 0, 0, 0);
      }
    }
    // bias add: combined offsets from LDS tables + prefetched ids
    v4sh cv = *(const v4sh*)&basc[(kt << 6) + (wave << 4) + (lhi << 2)];
    int bpj[4];
    #pragma unroll
    for (int j = 0; j < 4; j++) bpj[j] = (int)basp[(kt << 6) + (j << 4) + l15];
    #pragma unroll
    for (int j = 0; j < 4; j++){
      unsigned long long w = t64u[j];
      #pragma unroll
      for (int r = 0; r < 4; r++){
        int id = (int)((w >> (r << 4)) & 0xFFFF);
        s_acc[j][r] += b2f(cw[(int)cv[r] + id]) + b2f(pw[bpj[j] + id]);
      }
    }
    // defer-max online softmax (THR=6): shuffles only on rare trigger
    float lmax[4];
    bool grow = false;
    #pragma unroll
    for (int r = 0; r < 4; r++){
      lmax[r] = fmaxf(fmaxf(s_acc[0][r], s_acc[1][r]), fmaxf(s_acc[2][r], s_acc[3][r]));
      grow |= (lmax[r] > m_run[r] + 6.f);
    }
    if (__any(grow)){
      #pragma unroll
      for (int r = 0; r < 4; r++){
        float mx = lmax[r];
        mx = fmaxf(mx, __shfl_xor(mx, 1));
        mx = fmaxf(mx, __shfl_xor(mx, 2));
        mx = fmaxf(mx, __shfl_xor(mx, 4));
        mx = fmaxf(mx, __shfl_xor(mx, 8));
        float mnew = fmaxf(m_run[r], mx);
        float corr = exp2f(m_run[r] - mnew);
        m_run[r] = mnew;
        l_part[r] *= corr;
        #pragma unroll
        for (int j = 0; j < 4; j++) o_acc[j][r] *= corr;
      }
    }
    // P -> overlay into cw (own-wave rows only; program-ordered within wave)
    #pragma unroll
    for (int r = 0; r < 4; r++){
      int prow = (wave << 4) + (lhi << 2) + r;
      float ps = 0.f;
      #pragma unroll
      for (int j = 0; j < 4; j++){
        float p = exp2f(s_acc[j][r] - m_run[r]);
        ps += p;
        cw[prow*72 + (((j << 4) + l15) ^ ((prow & 7) << 3))] = f2b(p);
      }
      l_part[r] += ps;          // per-lane partial; reduced once at the end
    }
    // PV (same-wave P rows from cw overlay)
    int parow = (wave << 4) + l15;
    #pragma unroll
    for (int ks = 0; ks < 2; ks++){
      v8s pa = *(const v8s*)&cw[parow*72 + ((((ks << 2) + lhi) ^ (parow & 7)) << 3)];
      #pragma unroll
      for (int j = 0; j < 4; j++){
        int vrow = (j << 4) + l15;
        v8s vb = *(const v8s*)&v_lds[vrow*64 + ((((ks << 2) + lhi) ^ (vrow & 7)) << 3)];
        o_acc[j] = __builtin_amdgcn_mfma_f32_16x16x32_bf16(pa, vb, o_acc[j], 0, 0, 0);
      }
    }
  }
  // epilogue: reduce l partials across the 16 lanes of each row, store
  #pragma unroll
  for (int r = 0; r < 4; r++){
    float ls = l_part[r];
    ls += __shfl_xor(ls, 1); ls += __shfl_xor(ls, 2);
    ls += __shfl_xor(ls, 4); ls += __shfl_xor(ls, 8);
    int row = q0 + (wave << 4) + (lhi << 2) + r;
    float inv = 1.f / ls;
    #pragma unroll
    for (int j = 0; j < 4; j++)
      out[(size_t)((b << 10) + row)*1024 + (h << 6) + (j << 4) + l15] = o_acc[j][r] * inv;
  }
}

// ---------------------------------------------------------------------------
extern "C" void kernel_launch(void* const* d_in, const int* in_sizes, int n_in,
                              void* d_out, int out_size, void* d_ws, size_t ws_size,
                              hipStream_t stream)
{
  const float* hs  = (const float*)d_in[0];
  const float* rel = (const float*)d_in[1];
  const float* Wq  = (const float*)d_in[2];
  const float* bq  = (const float*)d_in[3];
  const float* Wk  = (const float*)d_in[4];
  const float* bk  = (const float*)d_in[5];
  const float* Wv  = (const float*)d_in[6];
  const float* bv  = (const float*)d_in[7];
  float* out = (float*)d_out;

  char* ws = (char*)d_ws;
  size_t off = 0;
  auto alloc = [&](size_t bytes) -> void* {
    void* p = ws + off; off += (bytes + 255) & ~(size_t)255; return p;
  };
  short*              idxt  = (short*)             alloc(2047 * 2);
  unsigned long long* tab64 = (unsigned long long*)alloc(2056 * 8);
  unsigned short* Xb   = (unsigned short*)alloc((size_t)4608*1024*2);
  unsigned short* Wt3  = (unsigned short*)alloc((size_t)3072*1024*2);
  unsigned short* Qa   = (unsigned short*)alloc((size_t)4608*1024*2);
  unsigned short* Ka   = (unsigned short*)alloc((size_t)4608*1024*2);
  unsigned short* Va   = (unsigned short*)alloc((size_t)4608*1024*2);
  unsigned short* VtT  = (unsigned short*)alloc((size_t)4096*1024*2);
  unsigned short* C2P  = (unsigned short*)alloc((size_t)4096*8192*2);
  unsigned short* P2C  = (unsigned short*)alloc((size_t)4096*8192*2);
  (void)                                  alloc(4096);   // OOB-read pad
  (void)ws_size; (void)in_sizes; (void)n_in; (void)out_size;

  pack_x<<<2313, 256, 0, stream>>>(hs, rel, Xb, idxt, tab64);
  transp3<<<dim3(256, 3), 256, 0, stream>>>(Wq, Wk, Wv, Wt3);

  const float alpha_q = 1.4426950408889634f / sqrtf(192.f);  // log2(e)/sqrt(D*3)
  gemm_qkv<<<864, 256, 0, stream>>>(Xb, Wt3, Qa, Ka, Va, bq, bk, bv, alpha_q);

  transp_b<<<dim3(256, 1, 4), 256, 0, stream>>>(Va, VtT);

  gemm_pos<<<dim3(128, 32), 256, 0, stream>>>(Qa, Ka, C2P, P2C);

  attn<<<1024, 256, 0, stream>>>(Qa, Ka, VtT, C2P, P2C, idxt, tab64, out);
}